// Round 11
// baseline (55.370 us; speedup 1.0000x reference)
//
#include <hip/hip_runtime.h>

// Chamfer min-matching loss, B=8, P=4096, D=2, fp32 — exact NN via spatial
// binning; LDS-staged, 4-lane-cooperative expanding-ring search.
// R10 lesson: 48KB LDS @256 blocks = 1 wave/SIMD -> latency-bound serial scan.
// Now: 40960B LDS (pts fp32 32KB + bin starts u16 8KB), 1024 blocks
// (4 blocks/CU, 4 waves/SIMD), 4 lanes per query splitting the candidate scan.

#define NB    8
#define NP    4096
#define BINS  64
#define NBIN  (BINS * BINS)
#define H     0.15625f          // 10.0 / 64
#define XMIN  -5.0f
#define INVH  6.4f
#define BSSTR (NBIN + 4)        // u32 stride; 16400 B, 16-aligned per target

__device__ __forceinline__ int binIdx(float x) {
    int i = (int)((x - XMIN) * INVH);
    return i < 0 ? 0 : (i > BINS - 1 ? BINS - 1 : i);
}

// ---- Kernel 1: counting sort, one block per (batch, side) ----
__global__ __launch_bounds__(256) void binSort(const float* __restrict__ pred,
                                               const float* __restrict__ gt,
                                               float2* __restrict__ P,      // [16][NP]
                                               unsigned* __restrict__ BS,   // [16][BSSTR]
                                               float* __restrict__ out) {
    __shared__ unsigned cnt[NBIN];      // 16 KB
    __shared__ unsigned waveTot[4];

    int t   = threadIdx.x;
    int s   = blockIdx.x;               // 0..15
    int tgt = ((s & 7) << 1) | (s >> 3);
    int b = tgt >> 1, side = tgt & 1;

    if (s == 0 && t == 0) *out = 0.0f;  // stream order: before binSearch atomics

    const float2* src = (const float2*)(side ? gt : pred) + (size_t)b * NP;
    float2*   dst = P  + (size_t)tgt * NP;
    unsigned* bs  = BS + (size_t)tgt * BSSTR;

#pragma unroll
    for (int i = 0; i < 16; ++i) cnt[t * 16 + i] = 0;
    __syncthreads();

    for (int i = t; i < NP; i += 256) {
        float2 p = src[i];
        atomicAdd(&cnt[binIdx(p.x) * BINS + binIdx(p.y)], 1u);
    }
    __syncthreads();

    unsigned local = 0;
#pragma unroll
    for (int i = 0; i < 16; ++i) local += cnt[t * 16 + i];

    unsigned inc = local;
#pragma unroll
    for (int o = 1; o < 64; o <<= 1) {
        unsigned n = __shfl_up(inc, o, 64);
        if ((t & 63) >= o) inc += n;
    }
    if ((t & 63) == 63) waveTot[t >> 6] = inc;
    __syncthreads();
    unsigned wbase = 0;
#pragma unroll
    for (int w = 0; w < 4; ++w) if (w < (t >> 6)) wbase += waveTot[w];
    unsigned run = wbase + inc - local;

#pragma unroll
    for (int i = 0; i < 16; ++i) {
        unsigned c = cnt[t * 16 + i];
        cnt[t * 16 + i] = run;
        run += c;
    }
    __syncthreads();

    for (int i = t; i < NBIN; i += 256) bs[i] = cnt[i];
    if (t == 0) bs[NBIN] = NP;
    __syncthreads();

    for (int i = t; i < NP; i += 256) {
        float2 p = src[i];
        unsigned pos = atomicAdd(&cnt[binIdx(p.x) * BINS + binIdx(p.y)], 1u);
        dst[pos] = p;
    }
}

// ---- Kernel 2: 4-lane-cooperative LDS ring search ----
__global__ __launch_bounds__(256) void binSearch(const float2* __restrict__ P,
                                                 const unsigned* __restrict__ BS,
                                                 float* __restrict__ out) {
    __shared__ __align__(16) float2 sp[NP];                // 32768 B
    __shared__ __align__(16) unsigned short sbs[NBIN];     // 8192 B -> 40960 total

    int t     = threadIdx.x;
    int bid   = blockIdx.x;        // 0..1023
    int qs    = bid & 15;          // dir*8 + b
    int slice = bid >> 4;          // 0..63 (64 queries each)
    int b = qs & 7, dir = qs >> 3;

    const float2* qarr = P + (size_t)(b * 2 + dir) * NP;
    int tgt = b * 2 + (1 - dir);
    const float2*   tp = P  + (size_t)tgt * NP;
    const unsigned* bs = BS + (size_t)tgt * BSSTR;

    // stage: 32 KB points + 4096 bin starts packed to u16
    const float4* tp4 = (const float4*)tp;
    float4*       sp4 = (float4*)sp;
#pragma unroll
    for (int i = 0; i < 8; ++i) sp4[t + i * 256] = tp4[t + i * 256];
    const uint4* bs4  = (const uint4*)bs;
    uint2*       sbs2 = (uint2*)sbs;
#pragma unroll
    for (int i = 0; i < 4; ++i) {
        uint4 v = bs4[t + i * 256];
        sbs2[t + i * 256] = make_uint2(v.x | (v.y << 16), v.z | (v.w << 16));
    }

    float2 q = qarr[slice * 64 + (t >> 2)];   // 4 lanes share a query
    int g = t & 3;
    __syncthreads();

    float qx = q.x, qy = q.y;
    int qi = binIdx(qx), qj = binIdx(qy);

    float best = 3.402823466e+38f;
    int r = 0;
    while (true) {
        int i0 = qi - r, i1 = qi + r, j0 = qj - r, j1 = qj + r;
        if (i0 < 0 && j0 < 0 && i1 >= BINS && j1 >= BINS) break;
        if (r >= 2) {
            float lb = (float)(r - 1) * H;
            if (lb * lb >= best) break;     // best is group-combined here
        }
        int ja = j0 < 0 ? 0 : j0, jb = j1 >= BINS ? BINS - 1 : j1;

        if (i0 >= 0) {                      // top row: one contiguous run
            int ei = i0 * BINS + jb + 1;
            unsigned s = sbs[i0 * BINS + ja];
            unsigned e = (ei >= NBIN) ? NP : sbs[ei];
            for (unsigned k = s + g; k < e; k += 4) {
                float2 pt = sp[k];
                float dx = qx - pt.x, dy = qy - pt.y;
                best = fminf(best, fmaf(dx, dx, dy * dy));
            }
        }
        if (r > 0) {
            if (i1 < BINS) {                // bottom row
                int ei = i1 * BINS + jb + 1;
                unsigned s = sbs[i1 * BINS + ja];
                unsigned e = (ei >= NBIN) ? NP : sbs[ei];
                for (unsigned k = s + g; k < e; k += 4) {
                    float2 pt = sp[k];
                    float dx = qx - pt.x, dy = qy - pt.y;
                    best = fminf(best, fmaf(dx, dx, dy * dy));
                }
            }
            int ia = (i0 + 1 < 0) ? 0 : i0 + 1;
            int ib = (i1 - 1 >= BINS) ? BINS - 1 : i1 - 1;
            if (j0 >= 0) {                  // left column
                for (int ii = ia; ii <= ib; ++ii) {
                    int idx = ii * BINS + j0;
                    unsigned s = sbs[idx];
                    unsigned e = (idx + 1 >= NBIN) ? NP : sbs[idx + 1];
                    for (unsigned k = s + g; k < e; k += 4) {
                        float2 pt = sp[k];
                        float dx = qx - pt.x, dy = qy - pt.y;
                        best = fminf(best, fmaf(dx, dx, dy * dy));
                    }
                }
            }
            if (j1 < BINS) {                // right column
                for (int ii = ia; ii <= ib; ++ii) {
                    int idx = ii * BINS + j1;
                    unsigned s = sbs[idx];
                    unsigned e = (idx + 1 >= NBIN) ? NP : sbs[idx + 1];
                    for (unsigned k = s + g; k < e; k += 4) {
                        float2 pt = sp[k];
                        float dx = qx - pt.x, dy = qy - pt.y;
                        best = fminf(best, fmaf(dx, dx, dy * dy));
                    }
                }
            }
        }
        // combine across the 4-lane group (uniform branches next iteration)
        best = fminf(best, __shfl_xor(best, 1, 64));
        best = fminf(best, __shfl_xor(best, 2, 64));
        ++r;
    }

    float v = (g == 0) ? sqrtf(fmaxf(best, 1e-12f)) : 0.0f;

#pragma unroll
    for (int o = 32; o > 0; o >>= 1) v += __shfl_down(v, o, 64);

    __shared__ float wsum[4];
    if ((t & 63) == 0) wsum[t >> 6] = v;
    __syncthreads();
    if (t == 0)
        atomicAdd(out, ((wsum[0] + wsum[1]) + (wsum[2] + wsum[3])) *
                           (0.5f / (float)(NB * NP)));
}

extern "C" void kernel_launch(void* const* d_in, const int* in_sizes, int n_in,
                              void* d_out, int out_size, void* d_ws, size_t ws_size,
                              hipStream_t stream) {
    const float* pred = (const float*)d_in[0];
    const float* gt   = (const float*)d_in[1];
    float*       out  = (float*)d_out;

    float2*   P  = (float2*)d_ws;                       // 512 KB
    unsigned* BS = (unsigned*)(P + (size_t)16 * NP);    // 16 * 16400 B

    (void)in_sizes; (void)n_in; (void)out_size; (void)ws_size;

    binSort<<<16, 256, 0, stream>>>(pred, gt, P, BS, out);
    binSearch<<<1024, 256, 0, stream>>>(P, BS, out);
}